// Round 6
// baseline (81.224 us; speedup 1.0000x reference)
//
#include <hip/hip_runtime.h>

#define NNODES 2048
#define NHEADS 8
#define NN (NNODES * NNODES)
#define CAP 512                 // per-row bucket capacity (λ=128, P(>512)≈0)

typedef float vfloat4 __attribute__((ext_vector_type(4)));

// Pass 1: bin edges by row. Entry packs (col, edge_idx): col<2048 (11b) in
// bits 18-28, e<2^18 in bits 0-17. Winner order doesn't matter (max-e wins).
__global__ __launch_bounds__(256) void bin_kernel(const int* __restrict__ ei, int E,
                                                  int* __restrict__ cnt,
                                                  unsigned* __restrict__ rowlist) {
    int e = blockIdx.x * blockDim.x + threadIdx.x;
    if (e >= E) return;
    const int r = ei[e];
    const int c = ei[E + e];
    const int slot = atomicAdd(&cnt[r], 1);
    if (slot < CAP) rowlist[r * CAP + slot] = ((unsigned)c << 18) | (unsigned)e;
}

// Pass 2: one block per row. Dense zero-fill of the row across all 8 head
// planes (issued first, overlaps the LDS winner resolution), then compact
// per-winner sigmoid compute + scattered overwrite of L2-hot lines.
__global__ __launch_bounds__(256) void row_kernel(const int* __restrict__ cnt,
                                                  const unsigned* __restrict__ rowlist,
                                                  const float* __restrict__ edge_score,
                                                  const float* __restrict__ W,
                                                  const float* __restrict__ b,
                                                  float* __restrict__ out) {
    __shared__ int wmap[NNODES];  // 8 KB: col -> max edge idx
    const int r = blockIdx.x;
    const int t = threadIdx.x;

    // Init LDS winner map.
#pragma unroll
    for (int i = 0; i < NNODES / 256; ++i) wmap[t + 256 * i] = -1;

    // Dense zero stores: 8 cols/thread × 8 heads = 16 float4 stores.
    // Independent of wmap — issue now so they overlap the list processing.
    {
        float* base = out + (size_t)r * NNODES + t * 8;
        const vfloat4 z = {0.f, 0.f, 0.f, 0.f};
#pragma unroll
        for (int h = 0; h < NHEADS; ++h) {
            vfloat4* p = reinterpret_cast<vfloat4*>(base + (size_t)h * NN);
            p[0] = z;
            p[1] = z;
        }
    }
    __syncthreads();  // wmap init visible (zero stores also drain here or later)

    const int n = min(cnt[r], CAP);
    for (int i = t; i < n; i += 256) {
        const unsigned p = rowlist[r * CAP + i];
        atomicMax(&wmap[p >> 18], (int)(p & 0x3FFFFu));
    }
    // Barrier: LDS winners final AND all dense zero stores drained to L2
    // (hipcc emits s_waitcnt vmcnt(0) lgkmcnt(0) before s_barrier), so the
    // scattered value stores below land strictly after the zeros.
    __syncthreads();

    const float fr = (float)r;
    for (int i = t; i < n; i += 256) {
        const unsigned p = rowlist[r * CAP + i];
        const int e = (int)(p & 0x3FFFFu);
        const int c = (int)(p >> 18);
        if (wmap[c] != e) continue;  // a later duplicate edge owns this cell
        const float fc = (float)c;
        const float sc = edge_score[e];
#pragma unroll
        for (int h = 0; h < NHEADS; ++h) {
            const float x = fmaf(fr, W[3 * h + 0],
                            fmaf(fc, W[3 * h + 1],
                            fmaf(sc, W[3 * h + 2], b[h])));
            const float s = 1.0f / (1.0f + __expf(-x));
            out[(size_t)h * NN + (size_t)r * NNODES + c] = s;
        }
    }
}

extern "C" void kernel_launch(void* const* d_in, const int* in_sizes, int n_in,
                              void* d_out, int out_size, void* d_ws, size_t ws_size,
                              hipStream_t stream) {
    const int*   edge_index = (const int*)d_in[0];   // (2, E) int32
    const float* edge_score = (const float*)d_in[1]; // (E,)
    const float* W          = (const float*)d_in[2]; // (H, 3)
    const float* b          = (const float*)d_in[3]; // (H,)
    float*       out        = (float*)d_out;         // (H, N, N)
    const int E = in_sizes[1];

    int*      cnt     = (int*)d_ws;                          // 8 KB
    unsigned* rowlist = (unsigned*)((char*)d_ws + NNODES * sizeof(int));  // 4 MiB

    hipMemsetAsync(cnt, 0, NNODES * sizeof(int), stream);    // tiny fill

    bin_kernel<<<(E + 255) / 256, 256, 0, stream>>>(edge_index, E, cnt, rowlist);
    row_kernel<<<NNODES, 256, 0, stream>>>(cnt, rowlist, edge_score, W, b, out);
}

// Round 7
// 71.036 us; speedup vs baseline: 1.1434x; 1.1434x over previous
//
#include <hip/hip_runtime.h>

#define NNODES 2048
#define NHEADS 8
#define NN (NNODES * NNODES)
#define SUB 8                   // sub-buckets per row (keyed by e&7) -> low atomic contention
#define CAP8 128                // per-sub-bucket capacity (lambda=16, P(>128)~0)
#define NBUCKET (NNODES * SUB)  // 16384 counters

typedef float vfloat4 __attribute__((ext_vector_type(4)));

// Zero the 64 KB counter array (own kernel: captured runtime fills are slow).
__global__ __launch_bounds__(256) void zero_kernel(int* __restrict__ cnt8) {
    cnt8[blockIdx.x * blockDim.x + threadIdx.x] = 0;
}

// Bin edges by (row, e&7). Entry packs (col<<18)|e (29 bits).
__global__ __launch_bounds__(256) void bin_kernel(const int* __restrict__ ei, int E,
                                                  int* __restrict__ cnt8,
                                                  unsigned* __restrict__ rowlist) {
    int e = blockIdx.x * blockDim.x + threadIdx.x;
    if (e >= E) return;
    const int r = ei[e];
    const int c = ei[E + e];
    const int bkt = r * SUB + (e & (SUB - 1));
    const int slot = atomicAdd(&cnt8[bkt], 1);
    if (slot < CAP8) rowlist[bkt * CAP8 + slot] = ((unsigned)c << 18) | (unsigned)e;
}

// One block per row: dense zeros (issued first, overlap list work), LDS
// winner resolution (last edge index wins), compact sigmoid + scatter.
__global__ __launch_bounds__(256) void row_kernel(const int* __restrict__ cnt8,
                                                  const unsigned* __restrict__ rowlist,
                                                  const float* __restrict__ edge_score,
                                                  const float* __restrict__ W,
                                                  const float* __restrict__ b,
                                                  float* __restrict__ out) {
    __shared__ int wmap[NNODES];  // 8 KB: col -> max edge idx
    const int r = blockIdx.x;
    const int t = threadIdx.x;

#pragma unroll
    for (int i = 0; i < NNODES / 256; ++i) wmap[t + 256 * i] = -1;

    // Dense zero stores: 8 cols/thread x 8 heads = 16 float4 stores.
    {
        float* base = out + (size_t)r * NNODES + t * 8;
        const vfloat4 z = {0.f, 0.f, 0.f, 0.f};
#pragma unroll
        for (int h = 0; h < NHEADS; ++h) {
            vfloat4* p = reinterpret_cast<vfloat4*>(base + (size_t)h * NN);
            p[0] = z;
            p[1] = z;
        }
    }
    __syncthreads();  // wmap init visible

    int ns[SUB];
#pragma unroll
    for (int s = 0; s < SUB; ++s) ns[s] = min(cnt8[r * SUB + s], CAP8);

#pragma unroll
    for (int s = 0; s < SUB; ++s) {
        const unsigned* lst = rowlist + (size_t)(r * SUB + s) * CAP8;
        for (int i = t; i < ns[s]; i += 256) {
            const unsigned p = lst[i];
            atomicMax(&wmap[p >> 18], (int)(p & 0x3FFFFu));
        }
    }
    // Winners final; dense zero stores drained (vmcnt(0) before s_barrier),
    // so the value stores below land strictly after the zeros.
    __syncthreads();

    const float fr = (float)r;
#pragma unroll
    for (int s = 0; s < SUB; ++s) {
        const unsigned* lst = rowlist + (size_t)(r * SUB + s) * CAP8;
        for (int i = t; i < ns[s]; i += 256) {
            const unsigned p = lst[i];
            const int e = (int)(p & 0x3FFFFu);
            const int c = (int)(p >> 18);
            if (wmap[c] != e) continue;  // a later duplicate edge owns this cell
            const float fc = (float)c;
            const float sc = edge_score[e];
#pragma unroll
            for (int h = 0; h < NHEADS; ++h) {
                const float x = fmaf(fr, W[3 * h + 0],
                                fmaf(fc, W[3 * h + 1],
                                fmaf(sc, W[3 * h + 2], b[h])));
                const float sgm = 1.0f / (1.0f + __expf(-x));
                out[(size_t)h * NN + (size_t)r * NNODES + c] = sgm;
            }
        }
    }
}

extern "C" void kernel_launch(void* const* d_in, const int* in_sizes, int n_in,
                              void* d_out, int out_size, void* d_ws, size_t ws_size,
                              hipStream_t stream) {
    const int*   edge_index = (const int*)d_in[0];   // (2, E) int32
    const float* edge_score = (const float*)d_in[1]; // (E,)
    const float* W          = (const float*)d_in[2]; // (H, 3)
    const float* b          = (const float*)d_in[3]; // (H,)
    float*       out        = (float*)d_out;         // (H, N, N)
    const int E = in_sizes[1];

    int*      cnt8    = (int*)d_ws;                                   // 64 KB
    unsigned* rowlist = (unsigned*)((char*)d_ws + NBUCKET * sizeof(int));  // 8 MiB

    zero_kernel<<<NBUCKET / 256, 256, 0, stream>>>(cnt8);
    bin_kernel<<<(E + 255) / 256, 256, 0, stream>>>(edge_index, E, cnt8, rowlist);
    row_kernel<<<NNODES, 256, 0, stream>>>(cnt8, rowlist, edge_score, W, b, out);
}